// Round 4
// baseline (123.607 us; speedup 1.0000x reference)
//
#include <hip/hip_runtime.h>

#define BB 4
#define TT 1024
#define DD 1024
#define UU 64
#define HW 32   // WIDTH/2

typedef unsigned short u16;
typedef __attribute__((ext_vector_type(4))) unsigned short u16x4;
typedef __attribute__((ext_vector_type(8))) unsigned short u16x8;
typedef __attribute__((ext_vector_type(8))) short bf16x8;   // raw bf16 bit patterns
typedef __attribute__((ext_vector_type(4))) float f32x4;
typedef __attribute__((ext_vector_type(2))) float f32x2;

// round-to-nearest-even fp32 -> bf16 (inputs are finite randn; no NaN handling)
__device__ __forceinline__ u16 bf16_rne(float f) {
  unsigned b = __builtin_bit_cast(unsigned, f);
  b += 0x7FFFu + ((b >> 16) & 1u);
  return (u16)(b >> 16);
}
__device__ __forceinline__ float bf16_tof(u16 h) {
  return __builtin_bit_cast(float, ((unsigned)h) << 16);
}

// ---------------------------------------------------------------------------
// wprep: UNCHANGED from R2. W fp32 -> transposed bf16 hi/lo, coalesced via LDS.
// ---------------------------------------------------------------------------
#define WLD 65
__global__ __launch_bounds__(256) void wprep_kernel(
    const float* __restrict__ Wt, const float* __restrict__ Wx,
    u16* __restrict__ Wht, u16* __restrict__ Wlt)
{
  __shared__ float ws[128 * WLD];          // 33 KB
  const int tid = threadIdx.x;
  const int d0  = blockIdx.x * 128;
  const float* __restrict__ src = blockIdx.y ? Wx : Wt;

  for (int i = tid; i < 2048; i += 256) {  // 2048 float4 = 128 rows x 16
    int r  = i >> 4;
    int c4 = (i & 15) << 2;
    float4 v = *(const float4*)(src + (size_t)(d0 + r) * UU + c4);
    float* w = ws + r * WLD + c4;
    w[0] = v.x; w[1] = v.y; w[2] = v.z; w[3] = v.w;
  }
  __syncthreads();

  for (int it = tid; it < 1024; it += 256) {   // 64 u x 16 d-octets
    int u = it >> 4, oct = it & 15;
    u16x8 h, l;
    #pragma unroll
    for (int j = 0; j < 8; ++j) {
      float v = ws[(8 * oct + j) * WLD + u];
      u16 hh = bf16_rne(v);
      h[j] = hh;
      l[j] = bf16_rne(v - bf16_tof(hh));       // exact residual (Sterbenz)
    }
    size_t off = (size_t)(blockIdx.y * UU + u) * DD + d0 + 8 * oct;
    *(u16x8*)(Wht + off) = h;
    *(u16x8*)(Wlt + off) = l;
  }
}

// ---------------------------------------------------------------------------
// proj v3: PROWS=32, K in two 512-halves (LDS 66.5 KB -> 2 blocks/CU).
// Each wave computes TWO 16-row A-tiles against ONE W fragment load ->
// W L2 traffic halves (128 MB -> 64 MB). Same 4-term bf16 split + exp
// epilogue (writes Eq = exp(-2(q+bh)), Ek = exp(-2k)).
// ---------------------------------------------------------------------------
#define PROWS 32
#define KH 512
#define KXLD (KH + 8)   // 520 u16 -> 1040 B row stride: 16-row frag reads 2-way max

__global__ __launch_bounds__(512, 4) void proj_mfma_kernel(
    const float* __restrict__ x, const u16* __restrict__ Wht,
    const u16* __restrict__ Wlt, const float* __restrict__ bh,
    float* __restrict__ qo, float* __restrict__ ko)
{
  __shared__ __align__(16) u16 Xh[PROWS][KXLD];   // 33.3 KB
  __shared__ __align__(16) u16 Xl[PROWS][KXLD];   // 33.3 KB

  const int tid  = threadIdx.x;
  const int row0 = blockIdx.x * PROWS;

  const int lane = tid & 63;
  const int wv   = tid >> 6;
  const int arow = lane & 15;
  const int g    = lane >> 4;
  const int u0   = wv * 16;

  f32x4 a00 = {0,0,0,0}, a01 = {0,0,0,0}, a02 = {0,0,0,0}, a03 = {0,0,0,0};
  f32x4 a10 = {0,0,0,0}, a11 = {0,0,0,0}, a12 = {0,0,0,0}, a13 = {0,0,0,0};

  #pragma unroll
  for (int ph = 0; ph < 2; ++ph) {
    const int kb = ph * KH;
    if (ph) __syncthreads();           // previous-phase LDS readers done

    // ---- stage 32 rows x 512 k of x -> bf16 hi/lo ----
    #pragma unroll
    for (int i = 0; i < 8; ++i) {
      int idx4 = tid + 512 * i;        // 0..4095 float4s (32 rows x 128)
      int r    = idx4 >> 7;            // row 0..31
      int c4   = (idx4 & 127) << 2;    // 0..508 floats
      float4 v = *(const float4*)(x + (size_t)(row0 + r) * DD + kb + c4);
      float vv[4] = {v.x, v.y, v.z, v.w};
      u16x4 hv, lv;
      #pragma unroll
      for (int j = 0; j < 4; ++j) {
        u16 hh = bf16_rne(vv[j]);
        hv[j] = hh;
        lv[j] = bf16_rne(vv[j] - bf16_tof(hh));
      }
      *(u16x4*)&Xh[r][c4] = hv;
      *(u16x4*)&Xl[r][c4] = lv;
    }
    __syncthreads();

    const u16* bhp = Wht + (size_t)(u0 + arow) * DD + kb + 8 * g;
    const u16* blp = Wlt + (size_t)(u0 + arow) * DD + kb + 8 * g;
    const u16* xh0 = &Xh[arow][8 * g];
    const u16* xl0 = &Xl[arow][8 * g];
    const u16* xh1 = &Xh[arow + 16][8 * g];
    const u16* xl1 = &Xl[arow + 16][8 * g];

    #pragma unroll 4
    for (int ks = 0; ks < 16; ++ks) {
      bf16x8 bhv = *(const bf16x8*)(bhp + 32 * ks);
      bf16x8 blv = *(const bf16x8*)(blp + 32 * ks);
      bf16x8 ah0 = *(const bf16x8*)(xh0 + 32 * ks);
      bf16x8 al0 = *(const bf16x8*)(xl0 + 32 * ks);
      bf16x8 ah1 = *(const bf16x8*)(xh1 + 32 * ks);
      bf16x8 al1 = *(const bf16x8*)(xl1 + 32 * ks);
      a00 = __builtin_amdgcn_mfma_f32_16x16x32_bf16(ah0, bhv, a00, 0, 0, 0);
      a01 = __builtin_amdgcn_mfma_f32_16x16x32_bf16(ah0, blv, a01, 0, 0, 0);
      a02 = __builtin_amdgcn_mfma_f32_16x16x32_bf16(al0, bhv, a02, 0, 0, 0);
      a03 = __builtin_amdgcn_mfma_f32_16x16x32_bf16(al0, blv, a03, 0, 0, 0);
      a10 = __builtin_amdgcn_mfma_f32_16x16x32_bf16(ah1, bhv, a10, 0, 0, 0);
      a11 = __builtin_amdgcn_mfma_f32_16x16x32_bf16(ah1, blv, a11, 0, 0, 0);
      a12 = __builtin_amdgcn_mfma_f32_16x16x32_bf16(al1, bhv, a12, 0, 0, 0);
      a13 = __builtin_amdgcn_mfma_f32_16x16x32_bf16(al1, blv, a13, 0, 0, 0);
    }
  }

  // D: lane l, reg r -> row 16*tile + 4*g + r, col u0 + arow
  const int col  = u0 + arow;
  const float bias = (col < UU) ? bh[col] : 0.0f;
  float* dst = (col < UU) ? (qo + col) : (ko + (col - UU));
  #pragma unroll
  for (int r = 0; r < 4; ++r) {
    float v0 = a00[r] + a01[r] + a02[r] + a03[r];
    float v1 = a10[r] + a11[r] + a12[r] + a13[r];
    dst[(size_t)(row0 +      4 * g + r) * UU] = __expf(-2.0f * (v0 + bias));
    dst[(size_t)(row0 + 16 + 4 * g + r) * UU] = __expf(-2.0f * (v1 + bias));
  }
}

// ---------------------------------------------------------------------------
// band v5: QBLK=16 query rows per block (256 blocks). Stage-3 xv reused
// across 16 rows (halves x L2 traffic, 148 -> 81 MB); stage-1 computes both
// row-octets per Ek load. Same arithmetic, same ordering -> same absmax.
// ---------------------------------------------------------------------------
#define QBLK 16
__global__ __launch_bounds__(512) void band_kernel(
    const float* __restrict__ x,  const float* __restrict__ eqg,
    const float* __restrict__ ekg, const float* __restrict__ Wa,
    const float* __restrict__ ba, float* __restrict__ out)
{
  __shared__ __align__(16) float at[80 * 16];    // [j][i], 5.1 KB

  const int tid  = threadIdx.x;
  const int bid  = blockIdx.x;
  const int tile = (bid & 7) * 32 + (bid >> 3);  // XCD swizzle (256 = 8*32)
  const int b    = tile >> 6;
  const int i0   = (tile & 63) * QBLK;

  const int jlo = max(0, i0 - HW);
  const int jhi = min(TT, i0 + QBLK - 1 + HW);   // exclusive
  const int NJ  = jhi - jlo;                     // 47..79

  const float bav = ba[0];

  // ---- stage 1: scores for both row-octets per Ek load ----
  {
    const int w    = tid >> 6;          // wave id: j-stride 8
    const int lane = tid & 63;
    const int g    = lane >> 3;         // row within octet
    const int uc   = (lane & 7) * 8;    // 8-u chunk per lane
    float eq0[8], eq1[8], wv[8];
    {
      const float* q0 = eqg + (size_t)(b * TT + i0 + g) * UU + uc;
      const float* q1 = q0 + 8 * UU;
      float4 c0 = *(const float4*)q0,      c1 = *(const float4*)(q0 + 4);
      float4 d0 = *(const float4*)q1,      d1 = *(const float4*)(q1 + 4);
      eq0[0]=c0.x; eq0[1]=c0.y; eq0[2]=c0.z; eq0[3]=c0.w;
      eq0[4]=c1.x; eq0[5]=c1.y; eq0[6]=c1.z; eq0[7]=c1.w;
      eq1[0]=d0.x; eq1[1]=d0.y; eq1[2]=d0.z; eq1[3]=d0.w;
      eq1[4]=d1.x; eq1[5]=d1.y; eq1[6]=d1.z; eq1[7]=d1.w;
      float4 wa0 = *(const float4*)(Wa + uc);
      float4 wa1 = *(const float4*)(Wa + uc + 4);
      wv[0]=wa0.x; wv[1]=wa0.y; wv[2]=wa0.z; wv[3]=wa0.w;
      wv[4]=wa1.x; wv[5]=wa1.y; wv[6]=wa1.z; wv[7]=wa1.w;
    }
    const int ig0 = i0 + g;
    const int ig1 = i0 + 8 + g;
    const float* kbase = ekg + (size_t)(b * TT + jlo) * UU + uc;
    for (int j = w; j < NJ; j += 8) {
      const float* kp = kbase + (size_t)j * UU;
      float4 k0 = *(const float4*)kp;
      float4 k1 = *(const float4*)(kp + 4);
      float ekv[8] = {k0.x, k0.y, k0.z, k0.w, k1.x, k1.y, k1.z, k1.w};
      float s0 = 0.f, s1 = 0.f;
      #pragma unroll
      for (int s = 0; s < 8; ++s) {
        float t0  = eq0[s] * ekv[s];
        float t1  = eq1[s] * ekv[s];
        float th0 = (1.0f - t0) * __builtin_amdgcn_rcpf(1.0f + t0);
        float th1 = (1.0f - t1) * __builtin_amdgcn_rcpf(1.0f + t1);
        s0 = __builtin_fmaf(th0, wv[s], s0);
        s1 = __builtin_fmaf(th1, wv[s], s1);
      }
      s0 += __shfl_xor(s0, 1); s1 += __shfl_xor(s1, 1);
      s0 += __shfl_xor(s0, 2); s1 += __shfl_xor(s1, 2);
      s0 += __shfl_xor(s0, 4); s1 += __shfl_xor(s1, 4);
      const int jg = jlo + j;
      if ((lane & 7) == 0) {
        at[j * 16 + g]     = (jg >= ig0 - HW && jg < ig0 + HW) ? (s0 + bav) : -1e30f;
        at[j * 16 + 8 + g] = (jg >= ig1 - HW && jg < ig1 + HW) ? (s1 + bav) : -1e30f;
      }
    }
  }
  __syncthreads();

  // ---- stage 2: softmax per row (wave handles rows 2w, 2w+1) ----
  {
    const int w = tid >> 6;
    const int l = tid & 63;
    #pragma unroll
    for (int rr2 = 0; rr2 < 2; ++rr2) {
      const int rr = 2 * w + rr2;
      float v0 = (l      < NJ) ? at[(l     ) * 16 + rr] : -1e30f;
      float v1 = (l + 64 < NJ) ? at[(l + 64) * 16 + rr] : -1e30f;
      float m = fmaxf(v0, v1);
      #pragma unroll
      for (int off = 32; off >= 1; off >>= 1) m = fmaxf(m, __shfl_xor(m, off));
      float e0 = __expf(v0 - m);
      float e1 = __expf(v1 - m);
      float ssum = e0 + e1;
      #pragma unroll
      for (int off = 32; off >= 1; off >>= 1) ssum += __shfl_xor(ssum, off);
      float inv = 1.0f / ssum;
      if (l      < NJ) at[(l     ) * 16 + rr] = e0 * inv;
      if (l + 64 < NJ) at[(l + 64) * 16 + rr] = e1 * inv;
    }
  }
  __syncthreads();

  // ---- stage 3: v = a @ x, xv reused across 16 rows ----
  {
    const f32x2 z = {0.f, 0.f};
    f32x2 vacc[16];
    #pragma unroll
    for (int i = 0; i < 16; ++i) vacc[i] = z;
    const float* xb = x + (size_t)(b * TT + jlo) * DD + 2 * tid;
    #pragma unroll 2
    for (int j = 0; j < NJ; ++j) {
      f32x2 xv = *(const f32x2*)(xb + (size_t)j * DD);
      float4 a0 = *(const float4*)(at + j * 16);
      float4 a1 = *(const float4*)(at + j * 16 + 4);
      float4 a2 = *(const float4*)(at + j * 16 + 8);
      float4 a3 = *(const float4*)(at + j * 16 + 12);
      float av[16] = {a0.x, a0.y, a0.z, a0.w, a1.x, a1.y, a1.z, a1.w,
                      a2.x, a2.y, a2.z, a2.w, a3.x, a3.y, a3.z, a3.w};
      #pragma unroll
      for (int i = 0; i < 16; ++i) {
        f32x2 s = {av[i], av[i]};
        vacc[i] = s * xv + vacc[i];     // v_pk_fma_f32
      }
    }
    float* ob = out + (size_t)(b * TT + i0) * DD + 2 * tid;
    #pragma unroll
    for (int i = 0; i < 16; ++i) *(f32x2*)(ob + (size_t)i * DD) = vacc[i];
  }
}

// ---------------------------------------------------------------------------
extern "C" void kernel_launch(void* const* d_in, const int* in_sizes, int n_in,
                              void* d_out, int out_size, void* d_ws, size_t ws_size,
                              hipStream_t stream) {
  const float* x  = (const float*)d_in[0];
  const float* Wt = (const float*)d_in[1];
  const float* Wx = (const float*)d_in[2];
  const float* bh = (const float*)d_in[3];
  const float* Wa = (const float*)d_in[4];
  const float* ba = (const float*)d_in[5];
  float* out = (float*)d_out;

  float* q = (float*)d_ws;                       // Eq [4096, 64] fp32, 1 MB
  float* k = q + (size_t)BB * TT * UU;           // Ek [4096, 64] fp32, 1 MB
  u16* Wht = (u16*)(k + (size_t)BB * TT * UU);   // [128, 1024] bf16, 256 KB
  u16* Wlt = Wht + (size_t)128 * DD;             // [128, 1024] bf16, 256 KB

  wprep_kernel<<<dim3(8, 2), dim3(256), 0, stream>>>(Wt, Wx, Wht, Wlt);
  proj_mfma_kernel<<<dim3((BB * TT) / PROWS), dim3(512), 0, stream>>>(x, Wht, Wlt, bh, q, k);
  band_kernel<<<dim3((BB * TT) / QBLK), dim3(512), 0, stream>>>(x, q, k, Wa, ba, out);
}

// Round 5
// 121.245 us; speedup vs baseline: 1.0195x; 1.0195x over previous
//
#include <hip/hip_runtime.h>

#define BB 4
#define TT 1024
#define DD 1024
#define UU 64
#define HW 32   // WIDTH/2

typedef unsigned short u16;
typedef __attribute__((ext_vector_type(4))) unsigned short u16x4;
typedef __attribute__((ext_vector_type(8))) unsigned short u16x8;
typedef __attribute__((ext_vector_type(8))) short bf16x8;   // raw bf16 bit patterns
typedef __attribute__((ext_vector_type(4))) float f32x4;
typedef __attribute__((ext_vector_type(2))) float f32x2;

// round-to-nearest-even fp32 -> bf16 (inputs are finite randn; no NaN handling)
__device__ __forceinline__ u16 bf16_rne(float f) {
  unsigned b = __builtin_bit_cast(unsigned, f);
  b += 0x7FFFu + ((b >> 16) & 1u);
  return (u16)(b >> 16);
}
__device__ __forceinline__ float bf16_tof(u16 h) {
  return __builtin_bit_cast(float, ((unsigned)h) << 16);
}

// ---------------------------------------------------------------------------
// wprep: UNCHANGED (R2-proven). W fp32 -> transposed bf16 hi/lo via LDS.
// ---------------------------------------------------------------------------
#define WLD 65
__global__ __launch_bounds__(256) void wprep_kernel(
    const float* __restrict__ Wt, const float* __restrict__ Wx,
    u16* __restrict__ Wht, u16* __restrict__ Wlt)
{
  __shared__ float ws[128 * WLD];          // 33 KB
  const int tid = threadIdx.x;
  const int d0  = blockIdx.x * 128;
  const float* __restrict__ src = blockIdx.y ? Wx : Wt;

  for (int i = tid; i < 2048; i += 256) {  // 2048 float4 = 128 rows x 16
    int r  = i >> 4;
    int c4 = (i & 15) << 2;
    float4 v = *(const float4*)(src + (size_t)(d0 + r) * UU + c4);
    float* w = ws + r * WLD + c4;
    w[0] = v.x; w[1] = v.y; w[2] = v.z; w[3] = v.w;
  }
  __syncthreads();

  for (int it = tid; it < 1024; it += 256) {   // 64 u x 16 d-octets
    int u = it >> 4, oct = it & 15;
    u16x8 h, l;
    #pragma unroll
    for (int j = 0; j < 8; ++j) {
      float v = ws[(8 * oct + j) * WLD + u];
      u16 hh = bf16_rne(v);
      h[j] = hh;
      l[j] = bf16_rne(v - bf16_tof(hh));       // exact residual (Sterbenz)
    }
    size_t off = (size_t)(blockIdx.y * UU + u) * DD + d0 + 8 * oct;
    *(u16x8*)(Wht + off) = h;
    *(u16x8*)(Wlt + off) = l;
  }
}

// ---------------------------------------------------------------------------
// proj: REVERTED to R3 form (PROWS=16, known-good ~7 us). bf16-split MFMA,
// exp epilogue writes Eq = exp(-2(q+bh)), Ek = exp(-2k).
// ---------------------------------------------------------------------------
#define PROWS 16
#define XLD (DD + 8)    // 1032 bf16 row stride: 2064 B -> 2-way max aliasing

__global__ __launch_bounds__(512) void proj_mfma_kernel(
    const float* __restrict__ x, const u16* __restrict__ Wht,
    const u16* __restrict__ Wlt, const float* __restrict__ bh,
    float* __restrict__ qo, float* __restrict__ ko)
{
  __shared__ __align__(16) u16 Xh[PROWS][XLD];   // 33 KB
  __shared__ __align__(16) u16 Xl[PROWS][XLD];   // 33 KB

  const int tid  = threadIdx.x;
  const int row0 = blockIdx.x * PROWS;

  {
    const float4* src = (const float4*)(x + (size_t)row0 * DD);
    #pragma unroll
    for (int i = 0; i < 8; ++i) {
      int idx4 = tid + 512 * i;
      int r    = idx4 >> 8;
      int k4   = (idx4 & 255) << 2;
      float4 v = src[idx4];
      float vv[4] = {v.x, v.y, v.z, v.w};
      u16x4 hv, lv;
      #pragma unroll
      for (int j = 0; j < 4; ++j) {
        u16 hh = bf16_rne(vv[j]);
        float lf = vv[j] - bf16_tof(hh);
        hv[j] = hh;
        lv[j] = bf16_rne(lf);
      }
      *(u16x4*)&Xh[r][k4] = hv;
      *(u16x4*)&Xl[r][k4] = lv;
    }
  }
  __syncthreads();

  const int lane = tid & 63;
  const int wv   = tid >> 6;
  const int arow = lane & 15;
  const int g    = lane >> 4;
  const int u0   = wv * 16;

  const u16* ah_p = &Xh[arow][8 * g];
  const u16* al_p = &Xl[arow][8 * g];
  const u16* bh_p = Wht + (size_t)(u0 + arow) * DD + 8 * g;
  const u16* bl_p = Wlt + (size_t)(u0 + arow) * DD + 8 * g;

  f32x4 acc0 = {0.f, 0.f, 0.f, 0.f};
  f32x4 acc1 = {0.f, 0.f, 0.f, 0.f};
  f32x4 acc2 = {0.f, 0.f, 0.f, 0.f};
  f32x4 acc3 = {0.f, 0.f, 0.f, 0.f};

  #pragma unroll 8
  for (int ks = 0; ks < 32; ++ks) {
    bf16x8 ah = *(const bf16x8*)(ah_p + 32 * ks);
    bf16x8 al = *(const bf16x8*)(al_p + 32 * ks);
    bf16x8 bhv = *(const bf16x8*)(bh_p + 32 * ks);
    bf16x8 blv = *(const bf16x8*)(bl_p + 32 * ks);
    acc0 = __builtin_amdgcn_mfma_f32_16x16x32_bf16(ah, bhv, acc0, 0, 0, 0);
    acc1 = __builtin_amdgcn_mfma_f32_16x16x32_bf16(ah, blv, acc1, 0, 0, 0);
    acc2 = __builtin_amdgcn_mfma_f32_16x16x32_bf16(al, bhv, acc2, 0, 0, 0);
    acc3 = __builtin_amdgcn_mfma_f32_16x16x32_bf16(al, blv, acc3, 0, 0, 0);
  }

  const int col  = u0 + arow;
  const float bias = (col < UU) ? bh[col] : 0.0f;
  float* dst = (col < UU) ? (qo + col) : (ko + (col - UU));
  #pragma unroll
  for (int r = 0; r < 4; ++r) {
    float v = acc0[r] + acc1[r] + acc2[r] + acc3[r];
    dst[(size_t)(row0 + 4 * g + r) * UU] = __expf(-2.0f * (v + bias));
  }
}

// ---------------------------------------------------------------------------
// band v6: QBLK=4 -> 1024 blocks -> 4 blocks/CU (32 waves/CU target, 2x R3).
// R4 proved band is occupancy/latency-sensitive (halving occupancy cost
// +9 us); this goes the other way. Same total score/FMA work as QBLK=8;
// stage-3 per-j ds_read halves to one b128; registers kept lean (<64 VGPR
// target). Same arithmetic + j-order -> same absmax.
// ---------------------------------------------------------------------------
#define QBLK 4
__global__ __launch_bounds__(512) void band_kernel(
    const float* __restrict__ x,  const float* __restrict__ eqg,
    const float* __restrict__ ekg, const float* __restrict__ Wa,
    const float* __restrict__ ba, float* __restrict__ out)
{
  __shared__ __align__(16) float at[72 * QBLK];  // [j][i], 1.2 KB

  const int tid  = threadIdx.x;
  const int bid  = blockIdx.x;
  const int tile = (bid & 7) * 128 + (bid >> 3); // XCD swizzle (1024 = 8*128)
  const int b    = tile >> 8;                    // 256 tiles per batch
  const int i0   = (tile & 255) * QBLK;

  const int jlo = max(0, i0 - HW);
  const int jhi = min(TT, i0 + QBLK - 1 + HW);   // exclusive
  const int NJ  = jhi - jlo;                     // 35..67

  const float bav = ba[0];

  // ---- stage 1: scores. 4 rows x 16-lane u-groups (4 u per lane) ----
  {
    const int w    = tid >> 6;          // wave id: j-stride 8
    const int lane = tid & 63;
    const int g    = lane >> 4;         // row 0..3
    const int c    = lane & 15;         // u-group
    const int uc   = c * 4;             // 4-u chunk per lane
    float eqv[4], wv[4];
    {
      float4 a0 = *(const float4*)(eqg + (size_t)(b * TT + i0 + g) * UU + uc);
      eqv[0] = a0.x; eqv[1] = a0.y; eqv[2] = a0.z; eqv[3] = a0.w;
      float4 wa0 = *(const float4*)(Wa + uc);
      wv[0] = wa0.x; wv[1] = wa0.y; wv[2] = wa0.z; wv[3] = wa0.w;
    }
    const int ig = i0 + g;
    const float* kbase = ekg + (size_t)(b * TT + jlo) * UU + uc;
    for (int j = w; j < NJ; j += 8) {
      float4 k0 = *(const float4*)(kbase + (size_t)j * UU);
      float ekv[4] = {k0.x, k0.y, k0.z, k0.w};
      float s0 = 0.f;
      #pragma unroll
      for (int s = 0; s < 4; ++s) {
        float t  = eqv[s] * ekv[s];
        float th = (1.0f - t) * __builtin_amdgcn_rcpf(1.0f + t);
        s0 = __builtin_fmaf(th, wv[s], s0);
      }
      s0 += __shfl_xor(s0, 1);
      s0 += __shfl_xor(s0, 2);
      s0 += __shfl_xor(s0, 4);
      s0 += __shfl_xor(s0, 8);
      const int jg = jlo + j;
      const bool inband = (jg >= ig - HW) && (jg < ig + HW);
      if (c == 0) at[j * QBLK + g] = inband ? (s0 + bav) : -1e30f;
    }
  }
  __syncthreads();

  // ---- stage 2: softmax per row over j (waves 0..3, one row each) ----
  {
    const int w = tid >> 6;
    const int l = tid & 63;
    if (w < QBLK) {
      float v0 = (l      < NJ) ? at[(l     ) * QBLK + w] : -1e30f;
      float v1 = (l + 64 < NJ) ? at[(l + 64) * QBLK + w] : -1e30f;
      float m = fmaxf(v0, v1);
      #pragma unroll
      for (int off = 32; off >= 1; off >>= 1) m = fmaxf(m, __shfl_xor(m, off));
      float e0 = __expf(v0 - m);
      float e1 = __expf(v1 - m);
      float ssum = e0 + e1;
      #pragma unroll
      for (int off = 32; off >= 1; off >>= 1) ssum += __shfl_xor(ssum, off);
      float inv = 1.0f / ssum;
      if (l      < NJ) at[(l     ) * QBLK + w] = e0 * inv;
      if (l + 64 < NJ) at[(l + 64) * QBLK + w] = e1 * inv;
    }
  }
  __syncthreads();

  // ---- stage 3: v = a @ x (thread owns f32x2 d-slice, 4 rows) ----
  {
    const f32x2 z = {0.f, 0.f};
    f32x2 vacc[QBLK];
    #pragma unroll
    for (int i = 0; i < QBLK; ++i) vacc[i] = z;
    const float* xb = x + (size_t)(b * TT + jlo) * DD + 2 * tid;
    #pragma unroll 4
    for (int j = 0; j < NJ; ++j) {
      f32x2 xv = *(const f32x2*)(xb + (size_t)j * DD);
      float4 a0 = *(const float4*)(at + j * QBLK);
      float av[QBLK] = {a0.x, a0.y, a0.z, a0.w};
      #pragma unroll
      for (int i = 0; i < QBLK; ++i) {
        f32x2 s = {av[i], av[i]};
        vacc[i] = s * xv + vacc[i];     // v_pk_fma_f32
      }
    }
    float* ob = out + (size_t)(b * TT + i0) * DD + 2 * tid;
    #pragma unroll
    for (int i = 0; i < QBLK; ++i) *(f32x2*)(ob + (size_t)i * DD) = vacc[i];
  }
}

// ---------------------------------------------------------------------------
extern "C" void kernel_launch(void* const* d_in, const int* in_sizes, int n_in,
                              void* d_out, int out_size, void* d_ws, size_t ws_size,
                              hipStream_t stream) {
  const float* x  = (const float*)d_in[0];
  const float* Wt = (const float*)d_in[1];
  const float* Wx = (const float*)d_in[2];
  const float* bh = (const float*)d_in[3];
  const float* Wa = (const float*)d_in[4];
  const float* ba = (const float*)d_in[5];
  float* out = (float*)d_out;

  float* q = (float*)d_ws;                       // Eq [4096, 64] fp32, 1 MB
  float* k = q + (size_t)BB * TT * UU;           // Ek [4096, 64] fp32, 1 MB
  u16* Wht = (u16*)(k + (size_t)BB * TT * UU);   // [128, 1024] bf16, 256 KB
  u16* Wlt = Wht + (size_t)128 * DD;             // [128, 1024] bf16, 256 KB

  wprep_kernel<<<dim3(8, 2), dim3(256), 0, stream>>>(Wt, Wx, Wht, Wlt);
  proj_mfma_kernel<<<dim3((BB * TT) / PROWS), dim3(512), 0, stream>>>(x, Wht, Wlt, bh, q, k);
  band_kernel<<<dim3((BB * TT) / QBLK), dim3(512), 0, stream>>>(x, q, k, Wa, ba, out);
}

// Round 6
// 119.445 us; speedup vs baseline: 1.0348x; 1.0151x over previous
//
#include <hip/hip_runtime.h>

#define BB 4
#define TT 1024
#define DD 1024
#define UU 64
#define HW 32   // WIDTH/2

typedef unsigned short u16;
typedef __attribute__((ext_vector_type(4))) unsigned short u16x4;
typedef __attribute__((ext_vector_type(8))) unsigned short u16x8;
typedef __attribute__((ext_vector_type(8))) short bf16x8;   // raw bf16 bit patterns
typedef __attribute__((ext_vector_type(4))) float f32x4;
typedef __attribute__((ext_vector_type(2))) float f32x2;

// round-to-nearest-even fp32 -> bf16 (inputs are finite randn; no NaN handling)
__device__ __forceinline__ u16 bf16_rne(float f) {
  unsigned b = __builtin_bit_cast(unsigned, f);
  b += 0x7FFFu + ((b >> 16) & 1u);
  return (u16)(b >> 16);
}
__device__ __forceinline__ float bf16_tof(u16 h) {
  return __builtin_bit_cast(float, ((unsigned)h) << 16);
}
// fp16 helpers (RNE via _Float16 cast; v_cvt_f16_f32 / v_cvt_f32_f16)
__device__ __forceinline__ u16 f16_bits(float f) {
  _Float16 h = (_Float16)f;
  return __builtin_bit_cast(u16, h);
}
__device__ __forceinline__ float f16_tof(u16 b) {
  return (float)__builtin_bit_cast(_Float16, b);
}

// ---------------------------------------------------------------------------
// wprep: UNCHANGED (R2-proven). W fp32 -> transposed bf16 hi/lo via LDS.
// ---------------------------------------------------------------------------
#define WLD 65
__global__ __launch_bounds__(256) void wprep_kernel(
    const float* __restrict__ Wt, const float* __restrict__ Wx,
    u16* __restrict__ Wht, u16* __restrict__ Wlt)
{
  __shared__ float ws[128 * WLD];          // 33 KB
  const int tid = threadIdx.x;
  const int d0  = blockIdx.x * 128;
  const float* __restrict__ src = blockIdx.y ? Wx : Wt;

  for (int i = tid; i < 2048; i += 256) {  // 2048 float4 = 128 rows x 16
    int r  = i >> 4;
    int c4 = (i & 15) << 2;
    float4 v = *(const float4*)(src + (size_t)(d0 + r) * UU + c4);
    float* w = ws + r * WLD + c4;
    w[0] = v.x; w[1] = v.y; w[2] = v.z; w[3] = v.w;
  }
  __syncthreads();

  for (int it = tid; it < 1024; it += 256) {   // 64 u x 16 d-octets
    int u = it >> 4, oct = it & 15;
    u16x8 h, l;
    #pragma unroll
    for (int j = 0; j < 8; ++j) {
      float v = ws[(8 * oct + j) * WLD + u];
      u16 hh = bf16_rne(v);
      h[j] = hh;
      l[j] = bf16_rne(v - bf16_tof(hh));       // exact residual (Sterbenz)
    }
    size_t off = (size_t)(blockIdx.y * UU + u) * DD + d0 + 8 * oct;
    *(u16x8*)(Wht + off) = h;
    *(u16x8*)(Wlt + off) = l;
  }
}

// ---------------------------------------------------------------------------
// proj: R3 form, UNCHANGED (PROWS=16, 256 blocks, known-good ~7 us).
// bf16-split MFMA; exp epilogue writes Eq = exp(-2(q+bh)), Ek = exp(-2k).
// ---------------------------------------------------------------------------
#define PROWS 16
#define XLD (DD + 8)    // 1032 bf16 row stride: 2064 B -> 2-way max aliasing

__global__ __launch_bounds__(512) void proj_mfma_kernel(
    const float* __restrict__ x, const u16* __restrict__ Wht,
    const u16* __restrict__ Wlt, const float* __restrict__ bh,
    float* __restrict__ qo, float* __restrict__ ko)
{
  __shared__ __align__(16) u16 Xh[PROWS][XLD];   // 33 KB
  __shared__ __align__(16) u16 Xl[PROWS][XLD];   // 33 KB

  const int tid  = threadIdx.x;
  const int row0 = blockIdx.x * PROWS;

  {
    const float4* src = (const float4*)(x + (size_t)row0 * DD);
    #pragma unroll
    for (int i = 0; i < 8; ++i) {
      int idx4 = tid + 512 * i;
      int r    = idx4 >> 8;
      int k4   = (idx4 & 255) << 2;
      float4 v = src[idx4];
      float vv[4] = {v.x, v.y, v.z, v.w};
      u16x4 hv, lv;
      #pragma unroll
      for (int j = 0; j < 4; ++j) {
        u16 hh = bf16_rne(vv[j]);
        float lf = vv[j] - bf16_tof(hh);
        hv[j] = hh;
        lv[j] = bf16_rne(lf);
      }
      *(u16x4*)&Xh[r][k4] = hv;
      *(u16x4*)&Xl[r][k4] = lv;
    }
  }
  __syncthreads();

  const int lane = tid & 63;
  const int wv   = tid >> 6;
  const int arow = lane & 15;
  const int g    = lane >> 4;
  const int u0   = wv * 16;

  const u16* ah_p = &Xh[arow][8 * g];
  const u16* al_p = &Xl[arow][8 * g];
  const u16* bh_p = Wht + (size_t)(u0 + arow) * DD + 8 * g;
  const u16* bl_p = Wlt + (size_t)(u0 + arow) * DD + 8 * g;

  f32x4 acc0 = {0.f, 0.f, 0.f, 0.f};
  f32x4 acc1 = {0.f, 0.f, 0.f, 0.f};
  f32x4 acc2 = {0.f, 0.f, 0.f, 0.f};
  f32x4 acc3 = {0.f, 0.f, 0.f, 0.f};

  #pragma unroll 8
  for (int ks = 0; ks < 32; ++ks) {
    bf16x8 ah = *(const bf16x8*)(ah_p + 32 * ks);
    bf16x8 al = *(const bf16x8*)(al_p + 32 * ks);
    bf16x8 bhv = *(const bf16x8*)(bh_p + 32 * ks);
    bf16x8 blv = *(const bf16x8*)(bl_p + 32 * ks);
    acc0 = __builtin_amdgcn_mfma_f32_16x16x32_bf16(ah, bhv, acc0, 0, 0, 0);
    acc1 = __builtin_amdgcn_mfma_f32_16x16x32_bf16(ah, blv, acc1, 0, 0, 0);
    acc2 = __builtin_amdgcn_mfma_f32_16x16x32_bf16(al, bhv, acc2, 0, 0, 0);
    acc3 = __builtin_amdgcn_mfma_f32_16x16x32_bf16(al, blv, acc3, 0, 0, 0);
  }

  const int col  = u0 + arow;
  const float bias = (col < UU) ? bh[col] : 0.0f;
  float* dst = (col < UU) ? (qo + col) : (ko + (col - UU));
  #pragma unroll
  for (int r = 0; r < 4; ++r) {
    float v = acc0[r] + acc1[r] + acc2[r] + acc3[r];
    dst[(size_t)(row0 + 4 * g + r) * UU] = __expf(-2.0f * (v + bias));
  }
}

// ---------------------------------------------------------------------------
// band v7: R3 structure (QBLK=8, 512 blocks — proven local optimum) with
// fp16 softmax weights. Stage 3 was LDS-broadcast-pipe-bound (2 ds_read_b128
// per j per thread, each fanning 16 B x 64 lanes). Stage 2 now writes
// weights as fp16 -> stage 3 reads ALL 8 rows in ONE b128 per j (LDS instrs
// halved); 8 v_cvt_f32_f16 per j run on the idle VALU. Weight rel-err
// <= 2^-11 -> absmax contribution ~4e-4 (margin proven >= 2x by R1).
// ---------------------------------------------------------------------------
__global__ __launch_bounds__(512) void band_kernel(
    const float* __restrict__ x,  const float* __restrict__ eqg,
    const float* __restrict__ ekg, const float* __restrict__ Wa,
    const float* __restrict__ ba, float* __restrict__ out)
{
  __shared__ __align__(16) float at[72 * 8];     // fp32 scores (stages 1-2)
  __shared__ __align__(16) u16  ah[72 * 8];      // fp16 weights (stage 3), 1.2 KB

  const int tid  = threadIdx.x;
  const int bid  = blockIdx.x;
  const int tile = (bid & 7) * 64 + (bid >> 3);  // XCD-locality swizzle
  const int b    = tile >> 7;
  const int i0   = (tile & 127) * 8;

  const int jlo = max(0, i0 - HW);
  const int jhi = min(TT, i0 + 8 - 1 + HW);      // exclusive
  const int NJ  = jhi - jlo;                     // 39..71

  const float bav = ba[0];

  // ---- stage 1: scores e[i][j] via t = Eq*Ek (direct global reads) ----
  {
    const int w    = tid >> 6;          // wave id: j-stride 8
    const int lane = tid & 63;
    const int g    = lane >> 3;         // i = i0 + g
    const int uc   = (lane & 7) * 8;    // 8-u chunk per lane
    float eqv[8], wv[8];
    {
      const float* qp = eqg + (size_t)(b * TT + i0 + g) * UU + uc;
      float4 a0 = *(const float4*)qp;
      float4 a1 = *(const float4*)(qp + 4);
      eqv[0] = a0.x; eqv[1] = a0.y; eqv[2] = a0.z; eqv[3] = a0.w;
      eqv[4] = a1.x; eqv[5] = a1.y; eqv[6] = a1.z; eqv[7] = a1.w;
      float4 wa0 = *(const float4*)(Wa + uc);
      float4 wa1 = *(const float4*)(Wa + uc + 4);
      wv[0] = wa0.x; wv[1] = wa0.y; wv[2] = wa0.z; wv[3] = wa0.w;
      wv[4] = wa1.x; wv[5] = wa1.y; wv[6] = wa1.z; wv[7] = wa1.w;
    }
    const int ig = i0 + g;
    const float* kbase = ekg + (size_t)(b * TT + jlo) * UU + uc;
    for (int j = w; j < NJ; j += 8) {
      const float* kp = kbase + (size_t)j * UU;
      float4 k0 = *(const float4*)kp;
      float4 k1 = *(const float4*)(kp + 4);
      float ekv[8] = {k0.x, k0.y, k0.z, k0.w, k1.x, k1.y, k1.z, k1.w};
      float s0 = 0.f;
      #pragma unroll
      for (int s = 0; s < 8; ++s) {
        float t  = eqv[s] * ekv[s];
        float th = (1.0f - t) * __builtin_amdgcn_rcpf(1.0f + t);
        s0 = __builtin_fmaf(th, wv[s], s0);
      }
      s0 += __shfl_xor(s0, 1);
      s0 += __shfl_xor(s0, 2);
      s0 += __shfl_xor(s0, 4);
      const int jg = jlo + j;
      const bool inband = (jg >= ig - HW) && (jg < ig + HW);
      if ((lane & 7) == 0) at[j * 8 + g] = inband ? (s0 + bav) : -1e30f;
    }
  }
  __syncthreads();

  // ---- stage 2: softmax per row over j; write weights as fp16 ----
  {
    const int row = tid >> 6;   // 0..7
    const int l   = tid & 63;
    float v0 = (l      < NJ) ? at[(l     ) * 8 + row] : -1e30f;
    float v1 = (l + 64 < NJ) ? at[(l + 64) * 8 + row] : -1e30f;
    float m = fmaxf(v0, v1);
    #pragma unroll
    for (int off = 32; off >= 1; off >>= 1) m = fmaxf(m, __shfl_xor(m, off));
    float e0 = __expf(v0 - m);
    float e1 = __expf(v1 - m);
    float ssum = e0 + e1;
    #pragma unroll
    for (int off = 32; off >= 1; off >>= 1) ssum += __shfl_xor(ssum, off);
    float inv = 1.0f / ssum;
    if (l      < NJ) ah[(l     ) * 8 + row] = f16_bits(e0 * inv);
    if (l + 64 < NJ) ah[(l + 64) * 8 + row] = f16_bits(e1 * inv);
  }
  __syncthreads();

  // ---- stage 3: v = a @ x. ONE ds_read_b128 per j (8 fp16 weights),
  //      8 v_cvt + 8 v_pk_fma_f32; unroll 4 keeps x-loads in flight. ----
  {
    const f32x2 z = {0.f, 0.f};
    f32x2 vacc[8];
    #pragma unroll
    for (int i = 0; i < 8; ++i) vacc[i] = z;
    const float* xb = x + (size_t)(b * TT + jlo) * DD + 2 * tid;
    #pragma unroll 4
    for (int j = 0; j < NJ; ++j) {
      f32x2 xv = *(const f32x2*)(xb + (size_t)j * DD);
      u16x8 a8 = *(const u16x8*)(ah + j * 8);
      #pragma unroll
      for (int i = 0; i < 8; ++i) {
        float av = f16_tof(a8[i]);
        f32x2 s = {av, av};
        vacc[i] = s * xv + vacc[i];     // v_pk_fma_f32
      }
    }
    float* ob = out + (size_t)(b * TT + i0) * DD + 2 * tid;
    #pragma unroll
    for (int i = 0; i < 8; ++i) *(f32x2*)(ob + (size_t)i * DD) = vacc[i];
  }
}

// ---------------------------------------------------------------------------
extern "C" void kernel_launch(void* const* d_in, const int* in_sizes, int n_in,
                              void* d_out, int out_size, void* d_ws, size_t ws_size,
                              hipStream_t stream) {
  const float* x  = (const float*)d_in[0];
  const float* Wt = (const float*)d_in[1];
  const float* Wx = (const float*)d_in[2];
  const float* bh = (const float*)d_in[3];
  const float* Wa = (const float*)d_in[4];
  const float* ba = (const float*)d_in[5];
  float* out = (float*)d_out;

  float* q = (float*)d_ws;                       // Eq [4096, 64] fp32, 1 MB
  float* k = q + (size_t)BB * TT * UU;           // Ek [4096, 64] fp32, 1 MB
  u16* Wht = (u16*)(k + (size_t)BB * TT * UU);   // [128, 1024] bf16, 256 KB
  u16* Wlt = Wht + (size_t)128 * DD;             // [128, 1024] bf16, 256 KB

  wprep_kernel<<<dim3(8, 2), dim3(256), 0, stream>>>(Wt, Wx, Wht, Wlt);
  proj_mfma_kernel<<<dim3((BB * TT) / PROWS), dim3(512), 0, stream>>>(x, Wht, Wlt, bh, q, k);
  band_kernel<<<dim3((BB * TT) / 8), dim3(512), 0, stream>>>(x, q, k, Wa, ba, out);
}

// Round 7
// 118.824 us; speedup vs baseline: 1.0403x; 1.0052x over previous
//
#include <hip/hip_runtime.h>

#define BB 4
#define TT 1024
#define DD 1024
#define UU 64
#define HW 32   // WIDTH/2

typedef unsigned short u16;
typedef __attribute__((ext_vector_type(4))) unsigned short u16x4;
typedef __attribute__((ext_vector_type(8))) unsigned short u16x8;
typedef __attribute__((ext_vector_type(8))) short bf16x8;   // raw bf16 bit patterns
typedef __attribute__((ext_vector_type(4))) float f32x4;
typedef __attribute__((ext_vector_type(2))) float f32x2;

// round-to-nearest-even fp32 -> bf16 (inputs are finite randn; no NaN handling)
__device__ __forceinline__ u16 bf16_rne(float f) {
  unsigned b = __builtin_bit_cast(unsigned, f);
  b += 0x7FFFu + ((b >> 16) & 1u);
  return (u16)(b >> 16);
}
__device__ __forceinline__ float bf16_tof(u16 h) {
  return __builtin_bit_cast(float, ((unsigned)h) << 16);
}

// ---------------------------------------------------------------------------
// wprep: UNCHANGED (R2-proven). W fp32 -> transposed bf16 hi/lo via LDS.
// ---------------------------------------------------------------------------
#define WLD 65
__global__ __launch_bounds__(256) void wprep_kernel(
    const float* __restrict__ Wt, const float* __restrict__ Wx,
    u16* __restrict__ Wht, u16* __restrict__ Wlt)
{
  __shared__ float ws[128 * WLD];          // 33 KB
  const int tid = threadIdx.x;
  const int d0  = blockIdx.x * 128;
  const float* __restrict__ src = blockIdx.y ? Wx : Wt;

  for (int i = tid; i < 2048; i += 256) {  // 2048 float4 = 128 rows x 16
    int r  = i >> 4;
    int c4 = (i & 15) << 2;
    float4 v = *(const float4*)(src + (size_t)(d0 + r) * UU + c4);
    float* w = ws + r * WLD + c4;
    w[0] = v.x; w[1] = v.y; w[2] = v.z; w[3] = v.w;
  }
  __syncthreads();

  for (int it = tid; it < 1024; it += 256) {   // 64 u x 16 d-octets
    int u = it >> 4, oct = it & 15;
    u16x8 h, l;
    #pragma unroll
    for (int j = 0; j < 8; ++j) {
      float v = ws[(8 * oct + j) * WLD + u];
      u16 hh = bf16_rne(v);
      h[j] = hh;
      l[j] = bf16_rne(v - bf16_tof(hh));       // exact residual (Sterbenz)
    }
    size_t off = (size_t)(blockIdx.y * UU + u) * DD + d0 + 8 * oct;
    *(u16x8*)(Wht + off) = h;
    *(u16x8*)(Wlt + off) = l;
  }
}

// ---------------------------------------------------------------------------
// proj: R3 form, UNCHANGED (PROWS=16, 256 blocks = full CU coverage,
// known-good). bf16-split MFMA; epilogue writes Eq = exp(-2(q+bh)),
// Ek = exp(-2k).  NOTE (R4 lesson): PROWS=32 halves the grid to 128 blocks
// -> half the CUs idle. 16 rows/block is forced by M=4096 / 256 CUs.
// ---------------------------------------------------------------------------
#define PROWS 16
#define XLD (DD + 8)    // 1032 bf16 row stride: 2064 B -> 2-way max aliasing

__global__ __launch_bounds__(512) void proj_mfma_kernel(
    const float* __restrict__ x, const u16* __restrict__ Wht,
    const u16* __restrict__ Wlt, const float* __restrict__ bh,
    float* __restrict__ qo, float* __restrict__ ko)
{
  __shared__ __align__(16) u16 Xh[PROWS][XLD];   // 33 KB
  __shared__ __align__(16) u16 Xl[PROWS][XLD];   // 33 KB

  const int tid  = threadIdx.x;
  const int row0 = blockIdx.x * PROWS;

  {
    const float4* src = (const float4*)(x + (size_t)row0 * DD);
    #pragma unroll
    for (int i = 0; i < 8; ++i) {
      int idx4 = tid + 512 * i;
      int r    = idx4 >> 8;
      int k4   = (idx4 & 255) << 2;
      float4 v = src[idx4];
      float vv[4] = {v.x, v.y, v.z, v.w};
      u16x4 hv, lv;
      #pragma unroll
      for (int j = 0; j < 4; ++j) {
        u16 hh = bf16_rne(vv[j]);
        float lf = vv[j] - bf16_tof(hh);
        hv[j] = hh;
        lv[j] = bf16_rne(lf);
      }
      *(u16x4*)&Xh[r][k4] = hv;
      *(u16x4*)&Xl[r][k4] = lv;
    }
  }
  __syncthreads();

  const int lane = tid & 63;
  const int wv   = tid >> 6;
  const int arow = lane & 15;
  const int g    = lane >> 4;
  const int u0   = wv * 16;

  const u16* ah_p = &Xh[arow][8 * g];
  const u16* al_p = &Xl[arow][8 * g];
  const u16* bh_p = Wht + (size_t)(u0 + arow) * DD + 8 * g;
  const u16* bl_p = Wlt + (size_t)(u0 + arow) * DD + 8 * g;

  f32x4 acc0 = {0.f, 0.f, 0.f, 0.f};
  f32x4 acc1 = {0.f, 0.f, 0.f, 0.f};
  f32x4 acc2 = {0.f, 0.f, 0.f, 0.f};
  f32x4 acc3 = {0.f, 0.f, 0.f, 0.f};

  #pragma unroll 8
  for (int ks = 0; ks < 32; ++ks) {
    bf16x8 ah = *(const bf16x8*)(ah_p + 32 * ks);
    bf16x8 al = *(const bf16x8*)(al_p + 32 * ks);
    bf16x8 bhv = *(const bf16x8*)(bh_p + 32 * ks);
    bf16x8 blv = *(const bf16x8*)(bl_p + 32 * ks);
    acc0 = __builtin_amdgcn_mfma_f32_16x16x32_bf16(ah, bhv, acc0, 0, 0, 0);
    acc1 = __builtin_amdgcn_mfma_f32_16x16x32_bf16(ah, blv, acc1, 0, 0, 0);
    acc2 = __builtin_amdgcn_mfma_f32_16x16x32_bf16(al, bhv, acc2, 0, 0, 0);
    acc3 = __builtin_amdgcn_mfma_f32_16x16x32_bf16(al, blv, acc3, 0, 0, 0);
  }

  const int col  = u0 + arow;
  const float bias = (col < UU) ? bh[col] : 0.0f;
  float* dst = (col < UU) ? (qo + col) : (ko + (col - UU));
  #pragma unroll
  for (int r = 0; r < 4; ++r) {
    float v = acc0[r] + acc1[r] + acc2[r] + acc3[r];
    dst[(size_t)(row0 + 4 * g + r) * UU] = __expf(-2.0f * (v + bias));
  }
}

// ---------------------------------------------------------------------------
// band v8: exact R3 structure (QBLK=8, 512 blocks, fp32 weights — proven
// optimum; fp16-weight experiment R6 cost +30-40 cyc/j-body in extracts,
// proving stage 3 is VALU-ISSUE-bound). One change vs R3: stage 3 is
// specialized for the interior case NJ==71 (120/128 tiles) so the trip
// count is a compile-time literal -> no per-iter bound check, deeper
// load pipelining. Identical arithmetic & order -> absmax 0.00390625.
// ---------------------------------------------------------------------------
__global__ __launch_bounds__(512) void band_kernel(
    const float* __restrict__ x,  const float* __restrict__ eqg,
    const float* __restrict__ ekg, const float* __restrict__ Wa,
    const float* __restrict__ ba, float* __restrict__ out)
{
  __shared__ __align__(16) float at[72 * 8];     // scores / weights, [j][i]

  const int tid  = threadIdx.x;
  const int bid  = blockIdx.x;
  const int tile = (bid & 7) * 64 + (bid >> 3);  // XCD-locality swizzle
  const int b    = tile >> 7;
  const int i0   = (tile & 127) * 8;

  const int jlo = max(0, i0 - HW);
  const int jhi = min(TT, i0 + 8 - 1 + HW);      // exclusive
  const int NJ  = jhi - jlo;                     // 39..71; ==71 for interior

  const float bav = ba[0];

  // ---- stage 1: scores e[i][j] via t = Eq*Ek (direct global reads) ----
  {
    const int w    = tid >> 6;          // wave id: j-stride 8
    const int lane = tid & 63;
    const int g    = lane >> 3;         // i = i0 + g
    const int uc   = (lane & 7) * 8;    // 8-u chunk per lane
    float eqv[8], wv[8];
    {
      const float* qp = eqg + (size_t)(b * TT + i0 + g) * UU + uc;
      float4 a0 = *(const float4*)qp;
      float4 a1 = *(const float4*)(qp + 4);
      eqv[0] = a0.x; eqv[1] = a0.y; eqv[2] = a0.z; eqv[3] = a0.w;
      eqv[4] = a1.x; eqv[5] = a1.y; eqv[6] = a1.z; eqv[7] = a1.w;
      float4 wa0 = *(const float4*)(Wa + uc);
      float4 wa1 = *(const float4*)(Wa + uc + 4);
      wv[0] = wa0.x; wv[1] = wa0.y; wv[2] = wa0.z; wv[3] = wa0.w;
      wv[4] = wa1.x; wv[5] = wa1.y; wv[6] = wa1.z; wv[7] = wa1.w;
    }
    const int ig = i0 + g;
    const float* kbase = ekg + (size_t)(b * TT + jlo) * UU + uc;
    for (int j = w; j < NJ; j += 8) {
      const float* kp = kbase + (size_t)j * UU;
      float4 k0 = *(const float4*)kp;
      float4 k1 = *(const float4*)(kp + 4);
      float ekv[8] = {k0.x, k0.y, k0.z, k0.w, k1.x, k1.y, k1.z, k1.w};
      float s0 = 0.f;
      #pragma unroll
      for (int s = 0; s < 8; ++s) {
        float t  = eqv[s] * ekv[s];
        float th = (1.0f - t) * __builtin_amdgcn_rcpf(1.0f + t);
        s0 = __builtin_fmaf(th, wv[s], s0);
      }
      s0 += __shfl_xor(s0, 1);
      s0 += __shfl_xor(s0, 2);
      s0 += __shfl_xor(s0, 4);
      const int jg = jlo + j;
      const bool inband = (jg >= ig - HW) && (jg < ig + HW);
      if ((lane & 7) == 0) at[j * 8 + g] = inband ? (s0 + bav) : -1e30f;
    }
  }
  __syncthreads();

  // ---- stage 2: softmax per row over j (one wave per row) ----
  {
    const int row = tid >> 6;   // 0..7
    const int l   = tid & 63;
    float v0 = (l      < NJ) ? at[(l     ) * 8 + row] : -1e30f;
    float v1 = (l + 64 < NJ) ? at[(l + 64) * 8 + row] : -1e30f;
    float m = fmaxf(v0, v1);
    #pragma unroll
    for (int off = 32; off >= 1; off >>= 1) m = fmaxf(m, __shfl_xor(m, off));
    float e0 = __expf(v0 - m);
    float e1 = __expf(v1 - m);
    float ssum = e0 + e1;
    #pragma unroll
    for (int off = 32; off >= 1; off >>= 1) ssum += __shfl_xor(ssum, off);
    float inv = 1.0f / ssum;
    if (l      < NJ) at[(l     ) * 8 + row] = e0 * inv;
    if (l + 64 < NJ) at[(l + 64) * 8 + row] = e1 * inv;
  }
  __syncthreads();

  // ---- stage 3: v = a @ x. NJ==71 fast path: literal trip count ----
  {
    const f32x2 z = {0.f, 0.f};
    f32x2 vacc[8];
    #pragma unroll
    for (int i = 0; i < 8; ++i) vacc[i] = z;
    const float* xb = x + (size_t)(b * TT + jlo) * DD + 2 * tid;

#define S3_BODY(J)                                                      \
    {                                                                   \
      f32x2 xv = *(const f32x2*)(xb + (size_t)(J) * DD);                \
      float4 a0 = *(const float4*)(at + (J) * 8);                       \
      float4 a1 = *(const float4*)(at + (J) * 8 + 4);                   \
      float av[8] = {a0.x, a0.y, a0.z, a0.w, a1.x, a1.y, a1.z, a1.w};   \
      _Pragma("unroll")                                                 \
      for (int i = 0; i < 8; ++i) {                                     \
        f32x2 s = {av[i], av[i]};                                       \
        vacc[i] = s * xv + vacc[i];     /* v_pk_fma_f32 */              \
      }                                                                 \
    }

    if (NJ == 71) {
      #pragma unroll 4
      for (int j = 0; j < 71; ++j) S3_BODY(j)
    } else {
      #pragma unroll 4
      for (int j = 0; j < NJ; ++j) S3_BODY(j)
    }
#undef S3_BODY

    float* ob = out + (size_t)(b * TT + i0) * DD + 2 * tid;
    #pragma unroll
    for (int i = 0; i < 8; ++i) *(f32x2*)(ob + (size_t)i * DD) = vacc[i];
  }
}

// ---------------------------------------------------------------------------
extern "C" void kernel_launch(void* const* d_in, const int* in_sizes, int n_in,
                              void* d_out, int out_size, void* d_ws, size_t ws_size,
                              hipStream_t stream) {
  const float* x  = (const float*)d_in[0];
  const float* Wt = (const float*)d_in[1];
  const float* Wx = (const float*)d_in[2];
  const float* bh = (const float*)d_in[3];
  const float* Wa = (const float*)d_in[4];
  const float* ba = (const float*)d_in[5];
  float* out = (float*)d_out;

  float* q = (float*)d_ws;                       // Eq [4096, 64] fp32, 1 MB
  float* k = q + (size_t)BB * TT * UU;           // Ek [4096, 64] fp32, 1 MB
  u16* Wht = (u16*)(k + (size_t)BB * TT * UU);   // [128, 1024] bf16, 256 KB
  u16* Wlt = Wht + (size_t)128 * DD;             // [128, 1024] bf16, 256 KB

  wprep_kernel<<<dim3(8, 2), dim3(256), 0, stream>>>(Wt, Wx, Wht, Wlt);
  proj_mfma_kernel<<<dim3((BB * TT) / PROWS), dim3(512), 0, stream>>>(x, Wht, Wlt, bh, q, k);
  band_kernel<<<dim3((BB * TT) / 8), dim3(512), 0, stream>>>(x, q, k, Wa, ba, out);
}

// Round 8
// 117.001 us; speedup vs baseline: 1.0565x; 1.0156x over previous
//
#include <hip/hip_runtime.h>

#define BB 4
#define TT 1024
#define DD 1024
#define UU 64
#define HW 32   // WIDTH/2

typedef unsigned short u16;
typedef __attribute__((ext_vector_type(4))) unsigned short u16x4;
typedef __attribute__((ext_vector_type(8))) unsigned short u16x8;
typedef __attribute__((ext_vector_type(8))) short bf16x8;   // raw bf16 bit patterns
typedef __attribute__((ext_vector_type(4))) float f32x4;
typedef __attribute__((ext_vector_type(2))) float f32x2;

// round-to-nearest-even fp32 -> bf16 (inputs are finite randn; no NaN handling)
__device__ __forceinline__ u16 bf16_rne(float f) {
  unsigned b = __builtin_bit_cast(unsigned, f);
  b += 0x7FFFu + ((b >> 16) & 1u);
  return (u16)(b >> 16);
}
__device__ __forceinline__ float bf16_tof(u16 h) {
  return __builtin_bit_cast(float, ((unsigned)h) << 16);
}

// ---------------------------------------------------------------------------
// wprep: W = [Wt | Wx] fp32 [1024 d][64 u] -> transposed bf16 hi/lo
// Wht/Wlt [128 u][1024 k]. Coalesced via LDS tile (padded stride 65).
// ---------------------------------------------------------------------------
#define WLD 65
__global__ __launch_bounds__(256) void wprep_kernel(
    const float* __restrict__ Wt, const float* __restrict__ Wx,
    u16* __restrict__ Wht, u16* __restrict__ Wlt)
{
  __shared__ float ws[128 * WLD];          // 33 KB
  const int tid = threadIdx.x;
  const int d0  = blockIdx.x * 128;
  const float* __restrict__ src = blockIdx.y ? Wx : Wt;

  for (int i = tid; i < 2048; i += 256) {  // 2048 float4 = 128 rows x 16
    int r  = i >> 4;
    int c4 = (i & 15) << 2;
    float4 v = *(const float4*)(src + (size_t)(d0 + r) * UU + c4);
    float* w = ws + r * WLD + c4;
    w[0] = v.x; w[1] = v.y; w[2] = v.z; w[3] = v.w;
  }
  __syncthreads();

  for (int it = tid; it < 1024; it += 256) {   // 64 u x 16 d-octets
    int u = it >> 4, oct = it & 15;
    u16x8 h, l;
    #pragma unroll
    for (int j = 0; j < 8; ++j) {
      float v = ws[(8 * oct + j) * WLD + u];
      u16 hh = bf16_rne(v);
      h[j] = hh;
      l[j] = bf16_rne(v - bf16_tof(hh));       // exact residual (Sterbenz)
    }
    size_t off = (size_t)(blockIdx.y * UU + u) * DD + d0 + 8 * oct;
    *(u16x8*)(Wht + off) = h;
    *(u16x8*)(Wlt + off) = l;
  }
}

// ---------------------------------------------------------------------------
// proj via bf16-split MFMA (PROWS=16, 256 blocks = full CU coverage).
// 4-term split: acc = xh*wh + xh*wl + xl*wh + xl*wl (~2^-18 rel err).
// Epilogue writes Eq = exp(-2(q+bh)), Ek = exp(-2k) so band needs no exp.
// R4 lesson: PROWS=32 halves the grid -> occupancy loss > L2-traffic gain.
// ---------------------------------------------------------------------------
#define PROWS 16
#define XLD (DD + 8)    // 1032 bf16 row stride: 2064 B -> 2-way max aliasing

__global__ __launch_bounds__(512) void proj_mfma_kernel(
    const float* __restrict__ x, const u16* __restrict__ Wht,
    const u16* __restrict__ Wlt, const float* __restrict__ bh,
    float* __restrict__ qo, float* __restrict__ ko)
{
  __shared__ __align__(16) u16 Xh[PROWS][XLD];   // 33 KB
  __shared__ __align__(16) u16 Xl[PROWS][XLD];   // 33 KB

  const int tid  = threadIdx.x;
  const int row0 = blockIdx.x * PROWS;

  {
    const float4* src = (const float4*)(x + (size_t)row0 * DD);
    #pragma unroll
    for (int i = 0; i < 8; ++i) {
      int idx4 = tid + 512 * i;
      int r    = idx4 >> 8;
      int k4   = (idx4 & 255) << 2;
      float4 v = src[idx4];
      float vv[4] = {v.x, v.y, v.z, v.w};
      u16x4 hv, lv;
      #pragma unroll
      for (int j = 0; j < 4; ++j) {
        u16 hh = bf16_rne(vv[j]);
        float lf = vv[j] - bf16_tof(hh);
        hv[j] = hh;
        lv[j] = bf16_rne(lf);
      }
      *(u16x4*)&Xh[r][k4] = hv;
      *(u16x4*)&Xl[r][k4] = lv;
    }
  }
  __syncthreads();

  const int lane = tid & 63;
  const int wv   = tid >> 6;
  const int arow = lane & 15;
  const int g    = lane >> 4;
  const int u0   = wv * 16;

  const u16* ah_p = &Xh[arow][8 * g];
  const u16* al_p = &Xl[arow][8 * g];
  const u16* bh_p = Wht + (size_t)(u0 + arow) * DD + 8 * g;
  const u16* bl_p = Wlt + (size_t)(u0 + arow) * DD + 8 * g;

  f32x4 acc0 = {0.f, 0.f, 0.f, 0.f};
  f32x4 acc1 = {0.f, 0.f, 0.f, 0.f};
  f32x4 acc2 = {0.f, 0.f, 0.f, 0.f};
  f32x4 acc3 = {0.f, 0.f, 0.f, 0.f};

  #pragma unroll 8
  for (int ks = 0; ks < 32; ++ks) {
    bf16x8 ah = *(const bf16x8*)(ah_p + 32 * ks);
    bf16x8 al = *(const bf16x8*)(al_p + 32 * ks);
    bf16x8 bhv = *(const bf16x8*)(bh_p + 32 * ks);
    bf16x8 blv = *(const bf16x8*)(bl_p + 32 * ks);
    acc0 = __builtin_amdgcn_mfma_f32_16x16x32_bf16(ah, bhv, acc0, 0, 0, 0);
    acc1 = __builtin_amdgcn_mfma_f32_16x16x32_bf16(ah, blv, acc1, 0, 0, 0);
    acc2 = __builtin_amdgcn_mfma_f32_16x16x32_bf16(al, bhv, acc2, 0, 0, 0);
    acc3 = __builtin_amdgcn_mfma_f32_16x16x32_bf16(al, blv, acc3, 0, 0, 0);
  }

  // D: lane l, reg r -> row 4*g + r, col u0 + arow; cols 0-63 -> Eq, 64-127 -> Ek
  const int col  = u0 + arow;
  const float bias = (col < UU) ? bh[col] : 0.0f;
  float* dst = (col < UU) ? (qo + col) : (ko + (col - UU));
  #pragma unroll
  for (int r = 0; r < 4; ++r) {
    float v = acc0[r] + acc1[r] + acc2[r] + acc3[r];
    dst[(size_t)(row0 + 4 * g + r) * UU] = __expf(-2.0f * (v + bias));
  }
}

// ---------------------------------------------------------------------------
// band (R3-final, proven optimum at 114.6 us): QBLK=8, 512 blocks, zero
// staging — stage 1 reads Eq/Ek direct from global (each row consumed once
// per block); tanh(q+k+bh) = (1-t)/(1+t), t = Eq*Ek; stage 3 on f32x2 ->
// v_pk_fma_f32, unroll 4. Falsified alternatives (do not revisit):
//   QBLK=16 (+9 us, occupancy loss), QBLK=4 (+6.6, redundancy+overhead),
//   fp16 weights (+4.8, cvt cost > LDS saving), literal-NJ split (+4.2).
// ---------------------------------------------------------------------------
__global__ __launch_bounds__(512) void band_kernel(
    const float* __restrict__ x,  const float* __restrict__ eqg,
    const float* __restrict__ ekg, const float* __restrict__ Wa,
    const float* __restrict__ ba, float* __restrict__ out)
{
  __shared__ __align__(16) float at[72 * 8];     // scores / weights, [j][i]

  const int tid  = threadIdx.x;
  const int bid  = blockIdx.x;
  const int tile = (bid & 7) * 64 + (bid >> 3);  // XCD-locality swizzle
  const int b    = tile >> 7;
  const int i0   = (tile & 127) * 8;

  const int jlo = max(0, i0 - HW);
  const int jhi = min(TT, i0 + 8 - 1 + HW);      // exclusive
  const int NJ  = jhi - jlo;                     // 39..71

  const float bav = ba[0];

  // ---- stage 1: scores e[i][j] via t = Eq*Ek (direct global reads) ----
  {
    const int w    = tid >> 6;          // wave id: j-stride 8
    const int lane = tid & 63;
    const int g    = lane >> 3;         // i = i0 + g
    const int uc   = (lane & 7) * 8;    // 8-u chunk per lane
    float eqv[8], wv[8];
    {
      const float* qp = eqg + (size_t)(b * TT + i0 + g) * UU + uc;
      float4 a0 = *(const float4*)qp;
      float4 a1 = *(const float4*)(qp + 4);
      eqv[0] = a0.x; eqv[1] = a0.y; eqv[2] = a0.z; eqv[3] = a0.w;
      eqv[4] = a1.x; eqv[5] = a1.y; eqv[6] = a1.z; eqv[7] = a1.w;
      float4 wa0 = *(const float4*)(Wa + uc);
      float4 wa1 = *(const float4*)(Wa + uc + 4);
      wv[0] = wa0.x; wv[1] = wa0.y; wv[2] = wa0.z; wv[3] = wa0.w;
      wv[4] = wa1.x; wv[5] = wa1.y; wv[6] = wa1.z; wv[7] = wa1.w;
    }
    const int ig = i0 + g;
    const float* kbase = ekg + (size_t)(b * TT + jlo) * UU + uc;
    for (int j = w; j < NJ; j += 8) {
      const float* kp = kbase + (size_t)j * UU;
      float4 k0 = *(const float4*)kp;
      float4 k1 = *(const float4*)(kp + 4);
      float ekv[8] = {k0.x, k0.y, k0.z, k0.w, k1.x, k1.y, k1.z, k1.w};
      float s0 = 0.f;
      #pragma unroll
      for (int s = 0; s < 8; ++s) {
        float t  = eqv[s] * ekv[s];
        float th = (1.0f - t) * __builtin_amdgcn_rcpf(1.0f + t);
        s0 = __builtin_fmaf(th, wv[s], s0);
      }
      s0 += __shfl_xor(s0, 1);
      s0 += __shfl_xor(s0, 2);
      s0 += __shfl_xor(s0, 4);
      const int jg = jlo + j;
      const bool inband = (jg >= ig - HW) && (jg < ig + HW);
      if ((lane & 7) == 0) at[j * 8 + g] = inband ? (s0 + bav) : -1e30f;
    }
  }
  __syncthreads();

  // ---- stage 2: softmax per row over j (one wave per row) ----
  {
    const int row = tid >> 6;   // 0..7
    const int l   = tid & 63;
    float v0 = (l      < NJ) ? at[(l     ) * 8 + row] : -1e30f;
    float v1 = (l + 64 < NJ) ? at[(l + 64) * 8 + row] : -1e30f;
    float m = fmaxf(v0, v1);
    #pragma unroll
    for (int off = 32; off >= 1; off >>= 1) m = fmaxf(m, __shfl_xor(m, off));
    float e0 = __expf(v0 - m);
    float e1 = __expf(v1 - m);
    float ssum = e0 + e1;
    #pragma unroll
    for (int off = 32; off >= 1; off >>= 1) ssum += __shfl_xor(ssum, off);
    float inv = 1.0f / ssum;
    if (l      < NJ) at[(l     ) * 8 + row] = e0 * inv;
    if (l + 64 < NJ) at[(l + 64) * 8 + row] = e1 * inv;
  }
  __syncthreads();

  // ---- stage 3: v = a @ x  (f32x2 slice -> v_pk_fma_f32, unroll 4) ----
  {
    const f32x2 z = {0.f, 0.f};
    f32x2 vacc[8];
    #pragma unroll
    for (int i = 0; i < 8; ++i) vacc[i] = z;
    const float* xb = x + (size_t)(b * TT + jlo) * DD + 2 * tid;
    #pragma unroll 4
    for (int j = 0; j < NJ; ++j) {
      f32x2 xv = *(const f32x2*)(xb + (size_t)j * DD);
      float4 a0 = *(const float4*)(at + j * 8);
      float4 a1 = *(const float4*)(at + j * 8 + 4);
      float av[8] = {a0.x, a0.y, a0.z, a0.w, a1.x, a1.y, a1.z, a1.w};
      #pragma unroll
      for (int i = 0; i < 8; ++i) {
        f32x2 s = {av[i], av[i]};
        vacc[i] = s * xv + vacc[i];     // v_pk_fma_f32
      }
    }
    float* ob = out + (size_t)(b * TT + i0) * DD + 2 * tid;
    #pragma unroll
    for (int i = 0; i < 8; ++i) *(f32x2*)(ob + (size_t)i * DD) = vacc[i];
  }
}

// ---------------------------------------------------------------------------
extern "C" void kernel_launch(void* const* d_in, const int* in_sizes, int n_in,
                              void* d_out, int out_size, void* d_ws, size_t ws_size,
                              hipStream_t stream) {
  const float* x  = (const float*)d_in[0];
  const float* Wt = (const float*)d_in[1];
  const float* Wx = (const float*)d_in[2];
  const float* bh = (const float*)d_in[3];
  const float* Wa = (const float*)d_in[4];
  const float* ba = (const float*)d_in[5];
  float* out = (float*)d_out;

  float* q = (float*)d_ws;                       // Eq [4096, 64] fp32, 1 MB
  float* k = q + (size_t)BB * TT * UU;           // Ek [4096, 64] fp32, 1 MB
  u16* Wht = (u16*)(k + (size_t)BB * TT * UU);   // [128, 1024] bf16, 256 KB
  u16* Wlt = Wht + (size_t)128 * DD;             // [128, 1024] bf16, 256 KB

  wprep_kernel<<<dim3(8, 2), dim3(256), 0, stream>>>(Wt, Wx, Wht, Wlt);
  proj_mfma_kernel<<<dim3((BB * TT) / PROWS), dim3(512), 0, stream>>>(x, Wht, Wlt, bh, q, k);
  band_kernel<<<dim3((BB * TT) / 8), dim3(512), 0, stream>>>(x, q, k, Wa, ba, out);
}